// Round 13
// baseline (398.200 us; speedup 1.0000x reference)
//
#include <hip/hip_runtime.h>
#include <hip/hip_bf16.h>
#include <cstdint>

typedef unsigned short u16;
typedef uint32_t u32;
typedef __attribute__((ext_vector_type(8))) u16 u16x8;
typedef __attribute__((ext_vector_type(4))) u16 u16x4;
typedef __attribute__((ext_vector_type(8))) __bf16 bf16x8;
typedef __attribute__((ext_vector_type(4))) float f32x4;

#define B_    8
#define T_    3137
#define H_    12
#define F_    16
#define D_    768
#define M1    25096      /* B_*T_ */
#define VSTR  3200       /* padded Vt row stride (64B-aligned rows) */
#define NSPL  8          /* cls split-K factor */
#define SPK   400        /* keys per cls split (8*400 >= 3137) */

__device__ __forceinline__ u16 f2bf(float f) {
  unsigned u = __float_as_uint(f);
  return (u16)((u + 0x7FFFu + ((u >> 16) & 1u)) >> 16);
}
__device__ __forceinline__ float b2f(u16 v) {
  return __uint_as_float(((unsigned)v) << 16);
}

// global -> LDS direct DMA, 16B per lane; dest = wave-uniform base + lane*16
#define GLL(g, l) __builtin_amdgcn_global_load_lds( \
    (const __attribute__((address_space(1))) void*)(g), \
    (__attribute__((address_space(3))) void*)(l), 16, 0, 0)

// inline-asm ds_read_b128: opaque to compiler -> no auto waitcnt drains
__device__ __forceinline__ void dsr(bf16x8& d, u32 abyte) {
  asm volatile("ds_read_b128 %0, %1" : "=v"(d) : "v"(abyte));
}

#define BARR  __builtin_amdgcn_s_barrier()
#define LGKM0 asm volatile("s_waitcnt lgkmcnt(0)")
#define SCB   __builtin_amdgcn_sched_barrier(0)
#define PRI1  __builtin_amdgcn_s_setprio(1)
#define PRI0  __builtin_amdgcn_s_setprio(0)

// ---------------- convert x (fp32) -> bf16 ----------------
__global__ __launch_bounds__(256) void k_cvt_x(const float* __restrict__ x,
                                               u16* __restrict__ xb, int n4) {
  int i = blockIdx.x * 256 + threadIdx.x;
  if (i >= n4) return;
  float4 v = ((const float4*)x)[i];
  u16x4 o = { f2bf(v.x), f2bf(v.y), f2bf(v.z), f2bf(v.w) };
  *(u16x4*)(xb + (size_t)i * 4) = o;
}

// ---------------- transpose fp32 RxC -> bf16 CxR (optional qkv column permutation) ----------------
__global__ __launch_bounds__(256) void k_transpose(const float* __restrict__ in,
                                                   u16* __restrict__ out,
                                                   int R, int C, int qkvperm) {
  __shared__ float tile[32][33];
  int c0 = blockIdx.x * 32, r0 = blockIdx.y * 32;
  int tx = threadIdx.x, ty = threadIdx.y;
  #pragma unroll
  for (int i = ty; i < 32; i += 8)
    tile[i][tx] = in[(size_t)(r0 + i) * C + c0 + tx];
  __syncthreads();
  #pragma unroll
  for (int i = ty; i < 32; i += 8) {
    int c = c0 + i;
    int orow;
    if (qkvperm) {
      int d = c / 36, rem = c - d * 36;
      int comp = rem / 12, hh = rem - comp * 12;
      orow = comp * 768 + hh * 64 + d;   // output col order: [comp][head][dim]
    } else {
      orow = c;
    }
    out[(size_t)orow * R + r0 + tx] = f2bf(tile[tx][i]);
  }
}

// ---------------- 128x128x(K=768) bf16 MFMA GEMM, BK=64 ----------------
// A staged via global_load_lds into 32KB dbuf (row-XOR swizzled, both-sides);
// B (L2-resident weight panel) read DIRECTLY from global into registers, one
// K-step ahead. FIFO per step: A-GLL(k+1) [4] then B-loads(k+1) [8] -> vmcnt(8)
// at step top retires exactly A(k); compiler's counted wait covers B regs.
// 3 blocks/CU (LDS 34.8KB, launch_bounds(256,3)).
// EPI==0: fp32 NT store.  EPI==1: Q(*0.125)/K via LDS->full-line rows; V via
// LDS transpose -> t-contiguous Vt writes.
template<int EPI, int NX>
__global__ __launch_bounds__(256, 3) void k_gemm(const u16* __restrict__ A,
                                                 const u16* __restrict__ Bm,
                                                 float* __restrict__ outF,
                                                 u16* __restrict__ Qb,
                                                 u16* __restrict__ Kb,
                                                 u16* __restrict__ Vt) {
  __shared__ u16 lds[17408];   // K-loop: 2 x 8192 u16 A-bufs (32KB); epilogue: [128][136]
  const int tid = threadIdx.x;
  const int lane = tid & 63;
  const int wid = tid >> 6;
  const int wr = wid >> 1, wc = wid & 1;
  const int li = lane & 15, lg = lane >> 4;

  // XCD-chunked swizzle (m204 bijective): hw block g (xcd=g&7) -> serial tile s
  const int nwg = NX * 197;
  const int q = nwg >> 3, r = nwg & 7;
  const int g = blockIdx.x;
  const int xcd = g & 7, pos = g >> 3;
  const int s = ((xcd < r) ? xcd * (q + 1) : r * (q + 1) + (xcd - r) * q) + pos;
  const int arow0 = (s / NX) * 128;
  const int brow0 = (s % NX) * 128;

  // A staging: wave wid fills rows [wid*32,+32); GLL c covers rows c*8..c*8+7.
  const int srow = wid * 32 + (lane >> 3);
  const int scol = ((lane & 7) ^ (lane >> 3)) * 8;
  const u16* gA = A + (size_t)(arow0 + srow) * 768 + scol;

  // B direct per-lane base: row = brow0 + wc*64 + li (+n*16), k = lg*8 (+step offsets)
  const u16* gBl = Bm + (size_t)(brow0 + wc * 64 + li) * 768 + lg * 8;

  const u32 ldsb = (u32)(uintptr_t)(__attribute__((address_space(3))) u16*)(&lds[0]);
  const u32 e0 = (u32)((lg ^ (li & 7)) * 16);
  const u32 e1 = (u32)(((lg + 4) ^ (li & 7)) * 16);
  const u32 aA = ldsb + (u32)(wr * 64 + li) * 128;   // + m*2048 + buf*16384 + e

  f32x4 acc[4][4] = {};
  bf16x8 bfr[4][2];

#define STAGE_A(TB, KS) do { const int kb_ = (KS) * 64; \
    _Pragma("unroll") for (int c_ = 0; c_ < 4; ++c_) \
      GLL(gA + kb_ + c_ * 8 * 768, lds + (TB) * 8192 + wid * 2048 + c_ * 512); \
  } while (0)

#define LOADB(KS) do { const int kb_ = (KS) * 64; \
    _Pragma("unroll") for (int n_ = 0; n_ < 4; ++n_) \
    _Pragma("unroll") for (int h_ = 0; h_ < 2; ++h_) \
      bfr[n_][h_] = *(const bf16x8*)(gBl + n_ * 16 * 768 + kb_ + h_ * 32); \
  } while (0)

#define STEP(CUR, KV) do { \
    asm volatile("s_waitcnt vmcnt(8)"); \
    BARR; \
    bf16x8 af[4][2]; \
    _Pragma("unroll") for (int m = 0; m < 4; ++m) { \
      dsr(af[m][0], aA + (CUR) * 16384 + m * 2048 + e0); \
      dsr(af[m][1], aA + (CUR) * 16384 + m * 2048 + e1); } \
    { const int ks_ = ((KV) + 1 < 12) ? (KV) + 1 : 11; STAGE_A((CUR) ^ 1, ks_); } \
    SCB; \
    LGKM0; SCB; PRI1; \
    _Pragma("unroll") for (int m = 0; m < 4; ++m) \
    _Pragma("unroll") for (int n = 0; n < 4; ++n) { \
      acc[m][n] = __builtin_amdgcn_mfma_f32_16x16x32_bf16(af[m][0], bfr[n][0], acc[m][n], 0, 0, 0); \
      acc[m][n] = __builtin_amdgcn_mfma_f32_16x16x32_bf16(af[m][1], bfr[n][1], acc[m][n], 0, 0, 0); } \
    PRI0; SCB; \
    { const int kn_ = ((KV) + 1 < 12) ? (KV) + 1 : 11; LOADB(kn_); } \
    SCB; \
    BARR; \
  } while (0)

  // prologue: A(0) GLLs first (FIFO-older), then B(0) loads
  STAGE_A(0, 0);
  LOADB(0);

  #pragma unroll 1
  for (int kk = 0; kk < 12; kk += 2) {
    STEP(0, kk);
    STEP(1, kk + 1);
  }
#undef STAGE_A
#undef LOADB
#undef STEP

  if (EPI == 0) {
    #pragma unroll
    for (int m = 0; m < 4; ++m)
      #pragma unroll
      for (int n = 0; n < 4; ++n) {
        const int colp = brow0 + wc * 64 + n * 16 + li;
        #pragma unroll
        for (int rr = 0; rr < 4; ++rr) {
          const int row = arow0 + wr * 64 + m * 16 + lg * 4 + rr;
          if (row < M1)
            __builtin_nontemporal_store(acc[m][n][rr], outF + (size_t)row * 768 + colp);
        }
      }
  } else {
    const int comp = brow0 / 768;              // uniform per block (128 | 768)
    const float qsc = (comp == 0) ? 0.125f : 1.0f;   // fold attention scale into Q
    const int b0r = arow0 / T_;
    const int RB = (b0r + 1) * T_;
    __syncthreads();
    if (comp < 2) {
      // Q/K: dump to LDS, then full-line 128B token-row writes (u16x4 x 16 lanes)
      u16* tl = &lds[0];                       // [128][136] u16
      #pragma unroll
      for (int m = 0; m < 4; ++m)
        #pragma unroll
        for (int n = 0; n < 4; ++n)
          #pragma unroll
          for (int rr = 0; rr < 4; ++rr)
            tl[(wr * 64 + m * 16 + lg * 4 + rr) * 136 + wc * 64 + n * 16 + li] =
                f2bf(acc[m][n][rr] * qsc);
      __syncthreads();
      u16* dst = (comp == 0) ? Qb : Kb;
      const int hh0 = (brow0 - comp * 768) >> 6;
      const int grp = tid >> 4, li2 = tid & 15;
      #pragma unroll
      for (int pass = 0; pass < 16; ++pass) {
        const int idx = pass * 16 + grp;
        const int row = idx >> 1, hl = idx & 1;
        const int rg = arow0 + row;
        if (rg >= M1) continue;
        const int bb = (rg >= RB) ? b0r + 1 : b0r;
        const int tt = rg - bb * T_;
        const size_t bh = (size_t)bb * H_ + hh0 + hl;
        *(u16x4*)(dst + ((bh * T_ + tt) << 6) + li2 * 4) =
            *(const u16x4*)(tl + row * 136 + hl * 64 + li2 * 4);
      }
    } else {
      // V: LDS transpose -> t-contiguous Vt row writes
      u16* tl = &lds[0];                       // [128][130] u16
      #pragma unroll
      for (int m = 0; m < 4; ++m)
        #pragma unroll
        for (int n = 0; n < 4; ++n)
          #pragma unroll
          for (int rr = 0; rr < 4; ++rr)
            tl[(wr * 64 + m * 16 + lg * 4 + rr) * 130 + wc * 64 + n * 16 + li] =
                f2bf(acc[m][n][rr]);
      __syncthreads();
      const int vcol0 = brow0 - 1536;
      #pragma unroll 1
      for (int cc = 0; cc < 32; ++cc) {
        const int c = wid * 32 + cc;
        const int vcol = vcol0 + c;
        const int hh = vcol >> 6, dd = vcol & 63;
        #pragma unroll
        for (int half = 0; half < 2; ++half) {
          const int tloc = half * 64 + lane;
          const int rg = arow0 + tloc;
          if (rg >= M1) continue;
          const int bb = (rg >= RB) ? b0r + 1 : b0r;
          const int tt = rg - bb * T_;
          Vt[(((size_t)bb * H_ + hh) * 64 + dd) * VSTR + tt] = tl[tloc * 130 + c];
        }
      }
    }
  }
}

// ---------------- spatial attention: one block per (b,f,h), 8 waves, K/V in LDS ----------------
// Q is pre-scaled by 0.125 (folded into GEMM1 epilogue).
__global__ __launch_bounds__(512, 2) void k_attn_sp(const u16* __restrict__ Qb,
                                                    const u16* __restrict__ Kb,
                                                    const u16* __restrict__ Vt,
                                                    u16* __restrict__ AO) {
  __shared__ u16 Ks[224 * 64];       // 28,672 B
  __shared__ u16 Vs[4 * 64 * 64];    // 32,768 B
  __shared__ u16 P[8][16 * 232];     // 59,392 B
  const int bid = blockIdx.x;
  const int h = bid % H_;
  const int f = (bid / H_) % F_;
  const int b = bid / (H_ * F_);
  const int tid = threadIdx.x;
  const int lane = tid & 63, w = tid >> 6;
  const int li = lane & 15, lg = lane >> 4;
  const size_t bh = (size_t)b * H_ + h;
  const u16* Qp = Qb + bh * T_ * 64;
  const u16* Kp = Kb + bh * T_ * 64;
  const u16* Vp = Vt + bh * 64 * VSTR;
  u16* ps = &P[w][0];

  if (w < 7) {
    #pragma unroll
    for (int p = 0; p < 4; ++p) {
      const int c = (w * 4 + p) * 64 + lane;        // 16B chunk id
      const int key = c >> 3, sp = lane & 7;
      const int tok = (key == 0) ? 0 : f * 196 + key;
      GLL(Kp + (size_t)tok * 64 + ((sp ^ (key & 7)) * 8), Ks + c * 8);
    }
  }
  {
    const int d = tid & 63, kg = (tid >> 6) & 3, sh = tid >> 8;
    #pragma unroll
    for (int st = 0; st < 2; ++st) {
      const int stt = sh + st * 2;
      const u16* src = Vp + (size_t)d * VSTR + f * 196 + stt * 64 + kg * 16;
      u16x4 a0 = *(const u16x4*)(src);
      u16x4 a1 = *(const u16x4*)(src + 4);
      u16x4 a2 = *(const u16x4*)(src + 8);
      u16x4 a3 = *(const u16x4*)(src + 12);
      if (stt == 0 && kg == 0) a0[0] = Vp[(size_t)d * VSTR];   // cls patch (t=0)
      u16* row = Vs + stt * 4096 + d * 64;
      const int s0 = (kg * 2) ^ (d & 7), s1 = (kg * 2 + 1) ^ (d & 7);
      u16x8 w0 = { a0[0], a0[1], a0[2], a0[3], a1[0], a1[1], a1[2], a1[3] };
      u16x8 w1 = { a2[0], a2[1], a2[2], a2[3], a3[0], a3[1], a3[2], a3[3] };
      *(u16x8*)(row + s0 * 8) = w0;
      *(u16x8*)(row + s1 * 8) = w1;
    }
  }
  __syncthreads();

  for (int mt = w; mt < 13; mt += 8) {
    const int pp = mt * 16 + li;
    const int ppc = pp < 196 ? pp : 195;
    const size_t tq = 1 + f * 196 + ppc;
    const bf16x8 qf0 = *(const bf16x8*)(Qp + tq * 64 + lg * 8);
    const bf16x8 qf1 = *(const bf16x8*)(Qp + tq * 64 + 32 + lg * 8);

    f32x4 s[14] = {};
    #pragma unroll
    for (int n = 0; n < 14; ++n) {
      const int key = n * 16 + li;
      const u16* kp = Ks + key * 64;
      const bf16x8 kf0 = *(const bf16x8*)(kp + ((lg ^ (li & 7)) * 8));
      const bf16x8 kf1 = *(const bf16x8*)(kp + (((lg + 4) ^ (li & 7)) * 8));
      s[n] = __builtin_amdgcn_mfma_f32_16x16x32_bf16(qf0, kf0, s[n], 0, 0, 0);
      s[n] = __builtin_amdgcn_mfma_f32_16x16x32_bf16(qf1, kf1, s[n], 0, 0, 0);
    }

    float rsum[4];
    #pragma unroll
    for (int r = 0; r < 4; ++r) {
      float vals[14];
      float mx = -1e30f;
      #pragma unroll
      for (int n = 0; n < 14; ++n) {
        const int key = n * 16 + li;
        vals[n] = (key < 197) ? s[n][r] : -1e30f;
        mx = fmaxf(mx, vals[n]);
      }
      #pragma unroll
      for (int msk = 1; msk < 16; msk <<= 1) mx = fmaxf(mx, __shfl_xor(mx, msk));
      float sum = 0.f;
      #pragma unroll
      for (int n = 0; n < 14; ++n) {
        const int key = n * 16 + li;
        float p = (key < 197) ? __expf(vals[n] - mx) : 0.f;
        sum += p;
        ps[(lg * 4 + r) * 232 + key] = f2bf(p);
      }
      #pragma unroll
      for (int msk = 1; msk < 16; msk <<= 1) sum += __shfl_xor(sum, msk);
      rsum[r] = sum;
    }

    f32x4 o[4] = {};
    #pragma unroll
    for (int ks = 0; ks < 7; ++ks) {
      const bf16x8 pf = *(const bf16x8*)(ps + li * 232 + ks * 32 + lg * 8);
      const int slot = ((ks & 1) * 4 + lg);
      #pragma unroll
      for (int n = 0; n < 4; ++n) {
        const int d = n * 16 + li;
        const bf16x8 vf = *(const bf16x8*)(Vs + (ks >> 1) * 4096 + d * 64 +
                                           ((slot ^ (li & 7)) * 8));
        o[n] = __builtin_amdgcn_mfma_f32_16x16x32_bf16(pf, vf, o[n], 0, 0, 0);
      }
    }

    // AO epilogue: stage 16x64 tile in ps (wave-private), write full 128B rows
    #pragma unroll
    for (int n = 0; n < 4; ++n)
      #pragma unroll
      for (int r = 0; r < 4; ++r)
        ps[(lg * 4 + r) * 64 + n * 16 + li] = f2bf(o[n][r] / rsum[r]);
    #pragma unroll
    for (int p2 = 0; p2 < 2; ++p2) {
      const int row = p2 * 8 + (lane >> 3);
      const int ch = lane & 7;
      const int ppo = mt * 16 + row;
      if (ppo < 196) {
        const size_t t = 1 + (size_t)f * 196 + ppo;
        *(u16x8*)(AO + ((size_t)b * T_ + t) * 768 + h * 64 + ch * 8) =
            *(const u16x8*)(ps + row * 64 + ch * 8);
      }
    }
  }
}

// ---------------- cls attention, split-K pass 1 (Q pre-scaled) ----------------
__global__ __launch_bounds__(256) void k_attn_cls1(const u16* __restrict__ Qb,
                                                   const u16* __restrict__ Kb,
                                                   const u16* __restrict__ Vt,
                                                   float* __restrict__ Pc) {
  __shared__ float qs[64];
  __shared__ float sv[SPK];
  __shared__ float red[8];
  const int bid = blockIdx.x;
  const int s = bid & (NSPL - 1);
  const int bh = bid >> 3;
  const u16* Qp = Qb + (size_t)bh * T_ * 64;
  const u16* Kp = Kb + (size_t)bh * T_ * 64;
  const u16* Vp = Vt + (size_t)bh * 64 * VSTR;
  const int base = s * SPK;
  const int nk = (T_ - base < SPK) ? (T_ - base) : SPK;
  const int tid = threadIdx.x;
  const int lane = tid & 63, w = tid >> 6;

  if (tid < 64) qs[tid] = b2f(Qp[tid]);
  for (int jj = nk + tid; jj < SPK; jj += 256) sv[jj] = 0.f;
  __syncthreads();

  float lmax = -1e30f;
  for (int jj = tid; jj < nk; jj += 256) {
    const u16* kp = Kp + (size_t)(base + jj) * 64;
    float acc = 0.f;
    #pragma unroll
    for (int d0 = 0; d0 < 64; d0 += 8) {
      u16x8 kv = *(const u16x8*)(kp + d0);
      #pragma unroll
      for (int e = 0; e < 8; ++e) acc += qs[d0 + e] * b2f(kv[e]);
    }
    sv[jj] = acc;
    lmax = fmaxf(lmax, acc);
  }
  #pragma unroll
  for (int msk = 32; msk; msk >>= 1) lmax = fmaxf(lmax, __shfl_xor(lmax, msk));
  if (lane == 0) red[w] = lmax;
  __syncthreads();
  const float bmax = fmaxf(fmaxf(red[0], red[1]), fmaxf(red[2], red[3]));

  float lsum = 0.f;
  for (int jj = tid; jj < nk; jj += 256) {
    float p = __expf(sv[jj] - bmax);
    sv[jj] = p;
    lsum += p;
  }
  #pragma unroll
  for (int msk = 32; msk; msk >>= 1) lsum += __shfl_xor(lsum, msk);
  if (lane == 0) red[4 + w] = lsum;
  __syncthreads();
  const float bsum = red[4] + red[5] + red[6] + red[7];

  const int d = tid >> 2, q4 = tid & 3;
  const u16* vp = Vp + (size_t)d * VSTR + base + q4 * (SPK / 4);
  const float* sp = &sv[q4 * (SPK / 4)];
  float o = 0.f;
  #pragma unroll
  for (int k4 = 0; k4 < SPK / 4; k4 += 4) {
    u16x4 vv = *(const u16x4*)(vp + k4);
    o += sp[k4]     * b2f(vv[0]) + sp[k4 + 1] * b2f(vv[1])
       + sp[k4 + 2] * b2f(vv[2]) + sp[k4 + 3] * b2f(vv[3]);
  }
  o += __shfl_xor(o, 1);
  o += __shfl_xor(o, 2);

  float* P = Pc + ((size_t)bh * NSPL + s) * 66;
  if (tid == 0) { P[0] = bmax; P[1] = bsum; }
  if (q4 == 0) P[2 + d] = o;
}

// ---------------- cls attention, split-K pass 2 ----------------
__global__ __launch_bounds__(64) void k_attn_cls2(const float* __restrict__ Pc,
                                                  u16* __restrict__ AO) {
  const int bh = blockIdx.x;
  const int d = threadIdx.x;
  const float* P = Pc + (size_t)bh * NSPL * 66;
  float m = -1e30f;
  #pragma unroll
  for (int s = 0; s < NSPL; ++s) m = fmaxf(m, P[s * 66]);
  float l = 0.f, o = 0.f;
  #pragma unroll
  for (int s = 0; s < NSPL; ++s) {
    const float wgt = __expf(P[s * 66] - m);
    l += wgt * P[s * 66 + 1];
    o += wgt * P[s * 66 + 2 + d];
  }
  const int b = bh / H_, h = bh - b * H_;
  AO[(size_t)b * T_ * 768 + h * 64 + d] = f2bf(o / l);
}

// ---------------- launch ----------------
extern "C" void kernel_launch(void* const* d_in, const int* in_sizes, int n_in,
                              void* d_out, int out_size, void* d_ws, size_t ws_size,
                              hipStream_t stream) {
  const float* x    = (const float*)d_in[0];
  const float* Wqkv = (const float*)d_in[1];
  const float* W0   = (const float*)d_in[2];
  float* out = (float*)d_out;
  char* ws = (char*)d_ws;

  u16* xb    = (u16*)(ws);                  // 25216*768*2 ; reused as AO
  u16* wqkvT = (u16*)(ws + 38731776);       // reused as Pc
  u16* w0T   = (u16*)(ws + 42270720);
  u16* Qb    = (u16*)(ws + 43450368);
  u16* Kb    = (u16*)(ws + 81997824);
  u16* Vt    = (u16*)(ws + 120545280);
  u16* AO = xb;
  float* Pc = (float*)wqkvT;

  k_cvt_x<<<dim3(18822), dim3(256), 0, stream>>>(x, xb, (M1 * D_) / 4);
  k_transpose<<<dim3(72, 24), dim3(32, 8), 0, stream>>>(Wqkv, wqkvT, 768, 2304, 1);
  k_transpose<<<dim3(24, 24), dim3(32, 8), 0, stream>>>(W0, w0T, 768, 768, 0);
  k_gemm<1, 18><<<dim3(18 * 197), dim3(256), 0, stream>>>(xb, wqkvT, nullptr, Qb, Kb, Vt);
  k_attn_sp<<<dim3(1536), dim3(512), 0, stream>>>(Qb, Kb, Vt, AO);
  k_attn_cls1<<<dim3(96 * NSPL), dim3(256), 0, stream>>>(Qb, Kb, Vt, Pc);
  k_attn_cls2<<<dim3(96), dim3(64), 0, stream>>>(Pc, AO);
  k_gemm<0, 6><<<dim3(6 * 197), dim3(256), 0, stream>>>(AO, w0T, out, nullptr, nullptr, nullptr);
}

// Round 14
// 276.426 us; speedup vs baseline: 1.4405x; 1.4405x over previous
//
#include <hip/hip_runtime.h>
#include <hip/hip_bf16.h>
#include <cstdint>

typedef unsigned short u16;
typedef uint32_t u32;
typedef __attribute__((ext_vector_type(8))) u16 u16x8;
typedef __attribute__((ext_vector_type(4))) u16 u16x4;
typedef __attribute__((ext_vector_type(8))) __bf16 bf16x8;
typedef __attribute__((ext_vector_type(4))) float f32x4;

#define B_    8
#define T_    3137
#define H_    12
#define F_    16
#define D_    768
#define M1    25096      /* B_*T_ */
#define VSTR  3200       /* padded Vt row stride (64B-aligned rows) */
#define NSPL  16         /* cls split-K factor */
#define SPK   208        /* keys per cls split (16*208 >= 3137, 208/4=52 %4==0) */

__device__ __forceinline__ u16 f2bf(float f) {
  unsigned u = __float_as_uint(f);
  return (u16)((u + 0x7FFFu + ((u >> 16) & 1u)) >> 16);
}
__device__ __forceinline__ float b2f(u16 v) {
  return __uint_as_float(((unsigned)v) << 16);
}

// global -> LDS direct DMA, 16B per lane; dest = wave-uniform base + lane*16
#define GLL(g, l) __builtin_amdgcn_global_load_lds( \
    (const __attribute__((address_space(1))) void*)(g), \
    (__attribute__((address_space(3))) void*)(l), 16, 0, 0)

// inline-asm ds_read_b128: opaque to compiler -> no auto waitcnt drains
__device__ __forceinline__ void dsr(bf16x8& d, u32 abyte) {
  asm volatile("ds_read_b128 %0, %1" : "=v"(d) : "v"(abyte));
}

#define BARR  __builtin_amdgcn_s_barrier()
#define LGKM0 asm volatile("s_waitcnt lgkmcnt(0)")
#define SCB   __builtin_amdgcn_sched_barrier(0)
#define PRI1  __builtin_amdgcn_s_setprio(1)
#define PRI0  __builtin_amdgcn_s_setprio(0)

// ---------------- convert x (fp32) -> bf16 ----------------
__global__ __launch_bounds__(256) void k_cvt_x(const float* __restrict__ x,
                                               u16* __restrict__ xb, int n4) {
  int i = blockIdx.x * 256 + threadIdx.x;
  if (i >= n4) return;
  float4 v = ((const float4*)x)[i];
  u16x4 o = { f2bf(v.x), f2bf(v.y), f2bf(v.z), f2bf(v.w) };
  *(u16x4*)(xb + (size_t)i * 4) = o;
}

// ---------------- transpose fp32 RxC -> bf16 CxR (optional qkv column permutation) ----------------
__global__ __launch_bounds__(256) void k_transpose(const float* __restrict__ in,
                                                   u16* __restrict__ out,
                                                   int R, int C, int qkvperm) {
  __shared__ float tile[32][33];
  int c0 = blockIdx.x * 32, r0 = blockIdx.y * 32;
  int tx = threadIdx.x, ty = threadIdx.y;
  #pragma unroll
  for (int i = ty; i < 32; i += 8)
    tile[i][tx] = in[(size_t)(r0 + i) * C + c0 + tx];
  __syncthreads();
  #pragma unroll
  for (int i = ty; i < 32; i += 8) {
    int c = c0 + i;
    int orow;
    if (qkvperm) {
      int d = c / 36, rem = c - d * 36;
      int comp = rem / 12, hh = rem - comp * 12;
      orow = comp * 768 + hh * 64 + d;   // output col order: [comp][head][dim]
    } else {
      orow = c;
    }
    out[(size_t)orow * R + r0 + tx] = f2bf(tile[tx][i]);
  }
}

// ---------------- 128x128x(K=768) bf16 MFMA GEMM, BK=64, conflict-free swizzle ----------------
// R12-proven structure: LDS rows 128B, byte ^= (row&7)<<4 both-sides; 2x32KB dbuf,
// vmcnt(8), 32 MFMA per barrier pair; XCD-chunked block swizzle.
// EPI==0: fp32 NT store to outF (GEMM2).  EPI==1: Q(*0.125)/K via LDS->full-line rows;
// V via LDS transpose -> t-contiguous Vt writes.
template<int EPI, int NX>
__global__ __launch_bounds__(256, 2) void k_gemm(const u16* __restrict__ A,
                                                 const u16* __restrict__ Bm,
                                                 float* __restrict__ outF,
                                                 u16* __restrict__ Qb,
                                                 u16* __restrict__ Kb,
                                                 u16* __restrict__ Vt) {
  __shared__ u16 lds[32768];   // 64KB: buf b at b*32KB; A 16KB then B 16KB
  const int tid = threadIdx.x;
  const int lane = tid & 63;
  const int wid = tid >> 6;
  const int wr = wid >> 1, wc = wid & 1;
  const int li = lane & 15, lg = lane >> 4;

  // XCD-chunked swizzle (m204 bijective): hw block g (xcd=g&7) -> serial tile s
  const int nwg = NX * 197;
  const int q = nwg >> 3, r = nwg & 7;
  const int g = blockIdx.x;
  const int xcd = g & 7, pos = g >> 3;
  const int s = ((xcd < r) ? xcd * (q + 1) : r * (q + 1) + (xcd - r) * q) + pos;
  const int arow0 = (s / NX) * 128;
  const int brow0 = (s % NX) * 128;

  // staging: wave wid fills rows [wid*32, +32); GLL c covers rows c*8..c*8+7 of slice.
  const int srow = wid * 32 + (lane >> 3);
  const int scol = ((lane & 7) ^ (lane >> 3)) * 8;
  const u16* gA = A  + (size_t)(arow0 + srow) * 768 + scol;
  const u16* gB = Bm + (size_t)(brow0 + srow) * 768 + scol;

  const u32 ldsb = (u32)(uintptr_t)(__attribute__((address_space(3))) u16*)(&lds[0]);
  const u32 e0 = (u32)((lg ^ (li & 7)) * 16);
  const u32 e1 = (u32)(((lg + 4) ^ (li & 7)) * 16);
  const u32 aA = ldsb + (u32)(wr * 64 + li) * 128;            // + m*2048 + buf*32768 + e
  const u32 aB = ldsb + 16384 + (u32)(wc * 64 + li) * 128;    // + n*2048 + buf*32768 + e

  f32x4 acc[4][4] = {};

#define STAGE(TB, KS) do { const int kb_ = (KS) * 64; \
    _Pragma("unroll") for (int c_ = 0; c_ < 4; ++c_) { \
      GLL(gA + kb_ + c_ * 8 * 768, lds + (TB) * 16384 + wid * 2048 + c_ * 512); \
      GLL(gB + kb_ + c_ * 8 * 768, lds + (TB) * 16384 + 8192 + wid * 2048 + c_ * 512); \
    } \
  } while (0)

#define STEP(CUR, KV) do { \
    { const int ks_ = ((KV) + 1 < 12) ? (KV) + 1 : 11; STAGE((CUR) ^ 1, ks_); } \
    asm volatile("s_waitcnt vmcnt(8)"); \
    BARR; \
    bf16x8 af[4][2], bfr[4][2]; \
    _Pragma("unroll") for (int m = 0; m < 4; ++m) { \
      dsr(af[m][0], aA + (CUR) * 32768 + m * 2048 + e0); \
      dsr(af[m][1], aA + (CUR) * 32768 + m * 2048 + e1); } \
    _Pragma("unroll") for (int n = 0; n < 4; ++n) { \
      dsr(bfr[n][0], aB + (CUR) * 32768 + n * 2048 + e0); \
      dsr(bfr[n][1], aB + (CUR) * 32768 + n * 2048 + e1); } \
    LGKM0; SCB; PRI1; \
    _Pragma("unroll") for (int m = 0; m < 4; ++m) \
    _Pragma("unroll") for (int n = 0; n < 4; ++n) { \
      acc[m][n] = __builtin_amdgcn_mfma_f32_16x16x32_bf16(af[m][0], bfr[n][0], acc[m][n], 0, 0, 0); \
      acc[m][n] = __builtin_amdgcn_mfma_f32_16x16x32_bf16(af[m][1], bfr[n][1], acc[m][n], 0, 0, 0); } \
    PRI0; BARR; \
  } while (0)

  STAGE(0, 0);   // prologue

  #pragma unroll 1
  for (int kk = 0; kk < 12; kk += 2) {
    STEP(0, kk);
    STEP(1, kk + 1);
  }
#undef STAGE
#undef STEP

  if (EPI == 0) {
    #pragma unroll
    for (int m = 0; m < 4; ++m)
      #pragma unroll
      for (int n = 0; n < 4; ++n) {
        const int colp = brow0 + wc * 64 + n * 16 + li;
        #pragma unroll
        for (int rr = 0; rr < 4; ++rr) {
          const int row = arow0 + wr * 64 + m * 16 + lg * 4 + rr;
          if (row < M1)
            __builtin_nontemporal_store(acc[m][n][rr], outF + (size_t)row * 768 + colp);
        }
      }
  } else {
    const int comp = brow0 / 768;              // uniform per block (128 | 768)
    const float qsc = (comp == 0) ? 0.125f : 1.0f;   // fold attention scale into Q
    const int b0r = arow0 / T_;
    const int RB = (b0r + 1) * T_;
    __syncthreads();
    if (comp < 2) {
      // Q/K: dump to LDS, then full-line 128B token-row writes (u16x4 x 16 lanes)
      u16* tl = &lds[0];                       // [128][136] u16
      #pragma unroll
      for (int m = 0; m < 4; ++m)
        #pragma unroll
        for (int n = 0; n < 4; ++n)
          #pragma unroll
          for (int rr = 0; rr < 4; ++rr)
            tl[(wr * 64 + m * 16 + lg * 4 + rr) * 136 + wc * 64 + n * 16 + li] =
                f2bf(acc[m][n][rr] * qsc);
      __syncthreads();
      u16* dst = (comp == 0) ? Qb : Kb;
      const int hh0 = (brow0 - comp * 768) >> 6;
      const int grp = tid >> 4, li2 = tid & 15;
      #pragma unroll
      for (int pass = 0; pass < 16; ++pass) {
        const int idx = pass * 16 + grp;
        const int row = idx >> 1, hl = idx & 1;
        const int rg = arow0 + row;
        if (rg >= M1) continue;
        const int bb = (rg >= RB) ? b0r + 1 : b0r;
        const int tt = rg - bb * T_;
        const size_t bh = (size_t)bb * H_ + hh0 + hl;
        *(u16x4*)(dst + ((bh * T_ + tt) << 6) + li2 * 4) =
            *(const u16x4*)(tl + row * 136 + hl * 64 + li2 * 4);
      }
    } else {
      // V: LDS transpose -> t-contiguous Vt row writes
      u16* tl = &lds[0];                       // [128][130] u16
      #pragma unroll
      for (int m = 0; m < 4; ++m)
        #pragma unroll
        for (int n = 0; n < 4; ++n)
          #pragma unroll
          for (int rr = 0; rr < 4; ++rr)
            tl[(wr * 64 + m * 16 + lg * 4 + rr) * 130 + wc * 64 + n * 16 + li] =
                f2bf(acc[m][n][rr]);
      __syncthreads();
      const int vcol0 = brow0 - 1536;
      #pragma unroll 1
      for (int cc = 0; cc < 32; ++cc) {
        const int c = wid * 32 + cc;
        const int vcol = vcol0 + c;
        const int hh = vcol >> 6, dd = vcol & 63;
        #pragma unroll
        for (int half = 0; half < 2; ++half) {
          const int tloc = half * 64 + lane;
          const int rg = arow0 + tloc;
          if (rg >= M1) continue;
          const int bb = (rg >= RB) ? b0r + 1 : b0r;
          const int tt = rg - bb * T_;
          Vt[(((size_t)bb * H_ + hh) * 64 + dd) * VSTR + tt] = tl[tloc * 130 + c];
        }
      }
    }
  }
}

// ---------------- spatial attention: one block per (b,f,h), 8 waves, K/V in LDS ----------------
// Q is pre-scaled by 0.125 (folded into GEMM1 epilogue).
__global__ __launch_bounds__(512, 2) void k_attn_sp(const u16* __restrict__ Qb,
                                                    const u16* __restrict__ Kb,
                                                    const u16* __restrict__ Vt,
                                                    u16* __restrict__ AO) {
  __shared__ u16 Ks[224 * 64];       // 28,672 B
  __shared__ u16 Vs[4 * 64 * 64];    // 32,768 B
  __shared__ u16 P[8][16 * 232];     // 59,392 B
  const int bid = blockIdx.x;
  const int h = bid % H_;
  const int f = (bid / H_) % F_;
  const int b = bid / (H_ * F_);
  const int tid = threadIdx.x;
  const int lane = tid & 63, w = tid >> 6;
  const int li = lane & 15, lg = lane >> 4;
  const size_t bh = (size_t)b * H_ + h;
  const u16* Qp = Qb + bh * T_ * 64;
  const u16* Kp = Kb + bh * T_ * 64;
  const u16* Vp = Vt + bh * 64 * VSTR;
  u16* ps = &P[w][0];

  if (w < 7) {
    #pragma unroll
    for (int p = 0; p < 4; ++p) {
      const int c = (w * 4 + p) * 64 + lane;        // 16B chunk id
      const int key = c >> 3, sp = lane & 7;
      const int tok = (key == 0) ? 0 : f * 196 + key;
      GLL(Kp + (size_t)tok * 64 + ((sp ^ (key & 7)) * 8), Ks + c * 8);
    }
  }
  {
    const int d = tid & 63, kg = (tid >> 6) & 3, sh = tid >> 8;
    #pragma unroll
    for (int st = 0; st < 2; ++st) {
      const int stt = sh + st * 2;
      const u16* src = Vp + (size_t)d * VSTR + f * 196 + stt * 64 + kg * 16;
      u16x4 a0 = *(const u16x4*)(src);
      u16x4 a1 = *(const u16x4*)(src + 4);
      u16x4 a2 = *(const u16x4*)(src + 8);
      u16x4 a3 = *(const u16x4*)(src + 12);
      if (stt == 0 && kg == 0) a0[0] = Vp[(size_t)d * VSTR];   // cls patch (t=0)
      u16* row = Vs + stt * 4096 + d * 64;
      const int s0 = (kg * 2) ^ (d & 7), s1 = (kg * 2 + 1) ^ (d & 7);
      u16x8 w0 = { a0[0], a0[1], a0[2], a0[3], a1[0], a1[1], a1[2], a1[3] };
      u16x8 w1 = { a2[0], a2[1], a2[2], a2[3], a3[0], a3[1], a3[2], a3[3] };
      *(u16x8*)(row + s0 * 8) = w0;
      *(u16x8*)(row + s1 * 8) = w1;
    }
  }
  __syncthreads();

  for (int mt = w; mt < 13; mt += 8) {
    const int pp = mt * 16 + li;
    const int ppc = pp < 196 ? pp : 195;
    const size_t tq = 1 + f * 196 + ppc;
    const bf16x8 qf0 = *(const bf16x8*)(Qp + tq * 64 + lg * 8);
    const bf16x8 qf1 = *(const bf16x8*)(Qp + tq * 64 + 32 + lg * 8);

    f32x4 s[14] = {};
    #pragma unroll
    for (int n = 0; n < 14; ++n) {
      const int key = n * 16 + li;
      const u16* kp = Ks + key * 64;
      const bf16x8 kf0 = *(const bf16x8*)(kp + ((lg ^ (li & 7)) * 8));
      const bf16x8 kf1 = *(const bf16x8*)(kp + (((lg + 4) ^ (li & 7)) * 8));
      s[n] = __builtin_amdgcn_mfma_f32_16x16x32_bf16(qf0, kf0, s[n], 0, 0, 0);
      s[n] = __builtin_amdgcn_mfma_f32_16x16x32_bf16(qf1, kf1, s[n], 0, 0, 0);
    }

    float rsum[4];
    #pragma unroll
    for (int r = 0; r < 4; ++r) {
      float vals[14];
      float mx = -1e30f;
      #pragma unroll
      for (int n = 0; n < 14; ++n) {
        const int key = n * 16 + li;
        vals[n] = (key < 197) ? s[n][r] : -1e30f;
        mx = fmaxf(mx, vals[n]);
      }
      #pragma unroll
      for (int msk = 1; msk < 16; msk <<= 1) mx = fmaxf(mx, __shfl_xor(mx, msk));
      float sum = 0.f;
      #pragma unroll
      for (int n = 0; n < 14; ++n) {
        const int key = n * 16 + li;
        float p = (key < 197) ? __expf(vals[n] - mx) : 0.f;
        sum += p;
        ps[(lg * 4 + r) * 232 + key] = f2bf(p);
      }
      #pragma unroll
      for (int msk = 1; msk < 16; msk <<= 1) sum += __shfl_xor(sum, msk);
      rsum[r] = sum;
    }

    f32x4 o[4] = {};
    #pragma unroll
    for (int ks = 0; ks < 7; ++ks) {
      const bf16x8 pf = *(const bf16x8*)(ps + li * 232 + ks * 32 + lg * 8);
      const int slot = ((ks & 1) * 4 + lg);
      #pragma unroll
      for (int n = 0; n < 4; ++n) {
        const int d = n * 16 + li;
        const bf16x8 vf = *(const bf16x8*)(Vs + (ks >> 1) * 4096 + d * 64 +
                                           ((slot ^ (li & 7)) * 8));
        o[n] = __builtin_amdgcn_mfma_f32_16x16x32_bf16(pf, vf, o[n], 0, 0, 0);
      }
    }

    // AO epilogue: stage 16x64 tile in ps (wave-private), write full 128B rows
    #pragma unroll
    for (int n = 0; n < 4; ++n)
      #pragma unroll
      for (int r = 0; r < 4; ++r)
        ps[(lg * 4 + r) * 64 + n * 16 + li] = f2bf(o[n][r] / rsum[r]);
    #pragma unroll
    for (int p2 = 0; p2 < 2; ++p2) {
      const int row = p2 * 8 + (lane >> 3);
      const int ch = lane & 7;
      const int ppo = mt * 16 + row;
      if (ppo < 196) {
        const size_t t = 1 + (size_t)f * 196 + ppo;
        *(u16x8*)(AO + ((size_t)b * T_ + t) * 768 + h * 64 + ch * 8) =
            *(const u16x8*)(ps + row * 64 + ch * 8);
      }
    }
  }
}

// ---------------- cls attention, split-K pass 1 (Q pre-scaled; 16 splits) ----------------
__global__ __launch_bounds__(256) void k_attn_cls1(const u16* __restrict__ Qb,
                                                   const u16* __restrict__ Kb,
                                                   const u16* __restrict__ Vt,
                                                   float* __restrict__ Pc) {
  __shared__ float qs[64];
  __shared__ float sv[SPK];
  __shared__ float red[8];
  const int bid = blockIdx.x;
  const int s = bid & (NSPL - 1);
  const int bh = bid >> 4;
  const u16* Qp = Qb + (size_t)bh * T_ * 64;
  const u16* Kp = Kb + (size_t)bh * T_ * 64;
  const u16* Vp = Vt + (size_t)bh * 64 * VSTR;
  const int base = s * SPK;
  const int nk0 = T_ - base;
  const int nk = (nk0 < SPK) ? nk0 : SPK;   // 208 (s<15) or 17 (s=15)
  const int tid = threadIdx.x;
  const int lane = tid & 63, w = tid >> 6;

  if (tid < 64) qs[tid] = b2f(Qp[tid]);
  for (int jj = nk + tid; jj < SPK; jj += 256) sv[jj] = 0.f;
  __syncthreads();

  float lmax = -1e30f;
  for (int jj = tid; jj < nk; jj += 256) {
    const u16* kp = Kp + (size_t)(base + jj) * 64;
    float acc = 0.f;
    #pragma unroll
    for (int d0 = 0; d0 < 64; d0 += 8) {
      u16x8 kv = *(const u16x8*)(kp + d0);
      #pragma unroll
      for (int e = 0; e < 8; ++e) acc += qs[d0 + e] * b2f(kv[e]);
    }
    sv[jj] = acc;
    lmax = fmaxf(lmax, acc);
  }
  #pragma unroll
  for (int msk = 32; msk; msk >>= 1) lmax = fmaxf(lmax, __shfl_xor(lmax, msk));
  if (lane == 0) red[w] = lmax;
  __syncthreads();
  const float bmax = fmaxf(fmaxf(red[0], red[1]), fmaxf(red[2], red[3]));

  float lsum = 0.f;
  for (int jj = tid; jj < nk; jj += 256) {
    float p = __expf(sv[jj] - bmax);
    sv[jj] = p;
    lsum += p;
  }
  #pragma unroll
  for (int msk = 32; msk; msk >>= 1) lsum += __shfl_xor(lsum, msk);
  if (lane == 0) red[4 + w] = lsum;
  __syncthreads();
  const float bsum = red[4] + red[5] + red[6] + red[7];

  const int d = tid >> 2, q4 = tid & 3;
  const u16* vp = Vp + (size_t)d * VSTR + base + q4 * (SPK / 4);
  const float* sp = &sv[q4 * (SPK / 4)];
  float o = 0.f;
  #pragma unroll
  for (int k4 = 0; k4 < SPK / 4; k4 += 4) {
    u16x4 vv = *(const u16x4*)(vp + k4);
    o += sp[k4]     * b2f(vv[0]) + sp[k4 + 1] * b2f(vv[1])
       + sp[k4 + 2] * b2f(vv[2]) + sp[k4 + 3] * b2f(vv[3]);
  }
  o += __shfl_xor(o, 1);
  o += __shfl_xor(o, 2);

  float* P = Pc + ((size_t)bh * NSPL + s) * 66;
  if (tid == 0) { P[0] = bmax; P[1] = bsum; }
  if (q4 == 0) P[2 + d] = o;
}

// ---------------- cls attention, split-K pass 2 ----------------
__global__ __launch_bounds__(64) void k_attn_cls2(const float* __restrict__ Pc,
                                                  u16* __restrict__ AO) {
  const int bh = blockIdx.x;
  const int d = threadIdx.x;
  const float* P = Pc + (size_t)bh * NSPL * 66;
  float m = -1e30f;
  #pragma unroll
  for (int s = 0; s < NSPL; ++s) m = fmaxf(m, P[s * 66]);
  float l = 0.f, o = 0.f;
  #pragma unroll
  for (int s = 0; s < NSPL; ++s) {
    const float wgt = __expf(P[s * 66] - m);
    l += wgt * P[s * 66 + 1];
    o += wgt * P[s * 66 + 2 + d];
  }
  const int b = bh / H_, h = bh - b * H_;
  AO[(size_t)b * T_ * 768 + h * 64 + d] = f2bf(o / l);
}

// ---------------- launch ----------------
extern "C" void kernel_launch(void* const* d_in, const int* in_sizes, int n_in,
                              void* d_out, int out_size, void* d_ws, size_t ws_size,
                              hipStream_t stream) {
  const float* x    = (const float*)d_in[0];
  const float* Wqkv = (const float*)d_in[1];
  const float* W0   = (const float*)d_in[2];
  float* out = (float*)d_out;
  char* ws = (char*)d_ws;

  u16* xb    = (u16*)(ws);                  // 25216*768*2 ; reused as AO
  u16* wqkvT = (u16*)(ws + 38731776);       // reused as Pc (96*16*66*4 = 405KB)
  u16* w0T   = (u16*)(ws + 42270720);
  u16* Qb    = (u16*)(ws + 43450368);
  u16* Kb    = (u16*)(ws + 81997824);
  u16* Vt    = (u16*)(ws + 120545280);
  u16* AO = xb;
  float* Pc = (float*)wqkvT;

  k_cvt_x<<<dim3(18822), dim3(256), 0, stream>>>(x, xb, (M1 * D_) / 4);
  k_transpose<<<dim3(72, 24), dim3(32, 8), 0, stream>>>(Wqkv, wqkvT, 768, 2304, 1);
  k_transpose<<<dim3(24, 24), dim3(32, 8), 0, stream>>>(W0, w0T, 768, 768, 0);
  k_gemm<1, 18><<<dim3(18 * 197), dim3(256), 0, stream>>>(xb, wqkvT, nullptr, Qb, Kb, Vt);
  k_attn_sp<<<dim3(1536), dim3(512), 0, stream>>>(Qb, Kb, Vt, AO);
  k_attn_cls1<<<dim3(96 * NSPL), dim3(256), 0, stream>>>(Qb, Kb, Vt, Pc);
  k_attn_cls2<<<dim3(96), dim3(64), 0, stream>>>(Pc, AO);
  k_gemm<0, 6><<<dim3(6 * 197), dim3(256), 0, stream>>>(AO, w0T, out, nullptr, nullptr, nullptr);
}

// Round 15
// 252.405 us; speedup vs baseline: 1.5776x; 1.0952x over previous
//
#include <hip/hip_runtime.h>
#include <hip/hip_bf16.h>
#include <cstdint>

typedef unsigned short u16;
typedef uint32_t u32;
typedef __attribute__((ext_vector_type(8))) u16 u16x8;
typedef __attribute__((ext_vector_type(4))) u16 u16x4;
typedef __attribute__((ext_vector_type(8))) __bf16 bf16x8;
typedef __attribute__((ext_vector_type(4))) float f32x4;

#define B_    8
#define T_    3137
#define H_    12
#define F_    16
#define D_    768
#define M1    25096      /* B_*T_ */
#define VSTR  3200       /* padded Vt row stride (64B-aligned rows) */
#define NSPL  16         /* cls split-K factor */
#define SPK   208        /* keys per cls split (16*208 >= 3137) */

__device__ __forceinline__ u16 f2bf(float f) {
  unsigned u = __float_as_uint(f);
  return (u16)((u + 0x7FFFu + ((u >> 16) & 1u)) >> 16);
}
__device__ __forceinline__ float b2f(u16 v) {
  return __uint_as_float(((unsigned)v) << 16);
}

// global -> LDS direct DMA, 16B per lane; dest = wave-uniform base + lane*16
#define GLL(g, l) __builtin_amdgcn_global_load_lds( \
    (const __attribute__((address_space(1))) void*)(g), \
    (__attribute__((address_space(3))) void*)(l), 16, 0, 0)

// inline-asm ds_read_b128: opaque to compiler -> no auto waitcnt drains
__device__ __forceinline__ void dsr(bf16x8& d, u32 abyte) {
  asm volatile("ds_read_b128 %0, %1" : "=v"(d) : "v"(abyte));
}

#define BARR  __builtin_amdgcn_s_barrier()
#define LGKM0 asm volatile("s_waitcnt lgkmcnt(0)")
#define SCB   __builtin_amdgcn_sched_barrier(0)
#define PRI1  __builtin_amdgcn_s_setprio(1)
#define PRI0  __builtin_amdgcn_s_setprio(0)

// ---------------- convert x (fp32) -> bf16 ----------------
__global__ __launch_bounds__(256) void k_cvt_x(const float* __restrict__ x,
                                               u16* __restrict__ xb, int n4) {
  int i = blockIdx.x * 256 + threadIdx.x;
  if (i >= n4) return;
  float4 v = ((const float4*)x)[i];
  u16x4 o = { f2bf(v.x), f2bf(v.y), f2bf(v.z), f2bf(v.w) };
  *(u16x4*)(xb + (size_t)i * 4) = o;
}

// ---------------- transpose fp32 RxC -> bf16 CxR (optional qkv column permutation) ----------------
__global__ __launch_bounds__(256) void k_transpose(const float* __restrict__ in,
                                                   u16* __restrict__ out,
                                                   int R, int C, int qkvperm) {
  __shared__ float tile[32][33];
  int c0 = blockIdx.x * 32, r0 = blockIdx.y * 32;
  int tx = threadIdx.x, ty = threadIdx.y;
  #pragma unroll
  for (int i = ty; i < 32; i += 8)
    tile[i][tx] = in[(size_t)(r0 + i) * C + c0 + tx];
  __syncthreads();
  #pragma unroll
  for (int i = ty; i < 32; i += 8) {
    int c = c0 + i;
    int orow;
    if (qkvperm) {
      int d = c / 36, rem = c - d * 36;
      int comp = rem / 12, hh = rem - comp * 12;
      orow = comp * 768 + hh * 64 + d;   // output col order: [comp][head][dim]
    } else {
      orow = c;
    }
    out[(size_t)orow * R + r0 + tx] = f2bf(tile[tx][i]);
  }
}

// ---------------- 128x128x(K=768) bf16 MFMA GEMM, BK=64, conflict-free swizzle ----------------
// R12-proven structure: LDS rows 128B, byte ^= (row&7)<<4 both-sides; 2x32KB dbuf,
// vmcnt(8), 32 MFMA per barrier pair; XCD-chunked block swizzle.
template<int EPI, int NX>
__global__ __launch_bounds__(256, 2) void k_gemm(const u16* __restrict__ A,
                                                 const u16* __restrict__ Bm,
                                                 float* __restrict__ outF,
                                                 u16* __restrict__ Qb,
                                                 u16* __restrict__ Kb,
                                                 u16* __restrict__ Vt) {
  __shared__ u16 lds[32768];   // 64KB: buf b at b*32KB; A 16KB then B 16KB
  const int tid = threadIdx.x;
  const int lane = tid & 63;
  const int wid = tid >> 6;
  const int wr = wid >> 1, wc = wid & 1;
  const int li = lane & 15, lg = lane >> 4;

  // XCD-chunked swizzle (m204 bijective): hw block g (xcd=g&7) -> serial tile s
  const int nwg = NX * 197;
  const int q = nwg >> 3, r = nwg & 7;
  const int g = blockIdx.x;
  const int xcd = g & 7, pos = g >> 3;
  const int s = ((xcd < r) ? xcd * (q + 1) : r * (q + 1) + (xcd - r) * q) + pos;
  const int arow0 = (s / NX) * 128;
  const int brow0 = (s % NX) * 128;

  // staging: wave wid fills rows [wid*32, +32); GLL c covers rows c*8..c*8+7 of slice.
  const int srow = wid * 32 + (lane >> 3);
  const int scol = ((lane & 7) ^ (lane >> 3)) * 8;
  const u16* gA = A  + (size_t)(arow0 + srow) * 768 + scol;
  const u16* gB = Bm + (size_t)(brow0 + srow) * 768 + scol;

  const u32 ldsb = (u32)(uintptr_t)(__attribute__((address_space(3))) u16*)(&lds[0]);
  const u32 e0 = (u32)((lg ^ (li & 7)) * 16);
  const u32 e1 = (u32)(((lg + 4) ^ (li & 7)) * 16);
  const u32 aA = ldsb + (u32)(wr * 64 + li) * 128;            // + m*2048 + buf*32768 + e
  const u32 aB = ldsb + 16384 + (u32)(wc * 64 + li) * 128;    // + n*2048 + buf*32768 + e

  f32x4 acc[4][4] = {};

#define STAGE(TB, KS) do { const int kb_ = (KS) * 64; \
    _Pragma("unroll") for (int c_ = 0; c_ < 4; ++c_) { \
      GLL(gA + kb_ + c_ * 8 * 768, lds + (TB) * 16384 + wid * 2048 + c_ * 512); \
      GLL(gB + kb_ + c_ * 8 * 768, lds + (TB) * 16384 + 8192 + wid * 2048 + c_ * 512); \
    } \
  } while (0)

#define STEP(CUR, KV) do { \
    { const int ks_ = ((KV) + 1 < 12) ? (KV) + 1 : 11; STAGE((CUR) ^ 1, ks_); } \
    asm volatile("s_waitcnt vmcnt(8)"); \
    BARR; \
    bf16x8 af[4][2], bfr[4][2]; \
    _Pragma("unroll") for (int m = 0; m < 4; ++m) { \
      dsr(af[m][0], aA + (CUR) * 32768 + m * 2048 + e0); \
      dsr(af[m][1], aA + (CUR) * 32768 + m * 2048 + e1); } \
    _Pragma("unroll") for (int n = 0; n < 4; ++n) { \
      dsr(bfr[n][0], aB + (CUR) * 32768 + n * 2048 + e0); \
      dsr(bfr[n][1], aB + (CUR) * 32768 + n * 2048 + e1); } \
    LGKM0; SCB; PRI1; \
    _Pragma("unroll") for (int m = 0; m < 4; ++m) \
    _Pragma("unroll") for (int n = 0; n < 4; ++n) { \
      acc[m][n] = __builtin_amdgcn_mfma_f32_16x16x32_bf16(af[m][0], bfr[n][0], acc[m][n], 0, 0, 0); \
      acc[m][n] = __builtin_amdgcn_mfma_f32_16x16x32_bf16(af[m][1], bfr[n][1], acc[m][n], 0, 0, 0); } \
    PRI0; BARR; \
  } while (0)

  STAGE(0, 0);   // prologue

  #pragma unroll 1
  for (int kk = 0; kk < 12; kk += 2) {
    STEP(0, kk);
    STEP(1, kk + 1);
  }
#undef STAGE
#undef STEP

  if (EPI == 0) {
    #pragma unroll
    for (int m = 0; m < 4; ++m)
      #pragma unroll
      for (int n = 0; n < 4; ++n) {
        const int colp = brow0 + wc * 64 + n * 16 + li;
        #pragma unroll
        for (int rr = 0; rr < 4; ++rr) {
          const int row = arow0 + wr * 64 + m * 16 + lg * 4 + rr;
          if (row < M1)
            __builtin_nontemporal_store(acc[m][n][rr], outF + (size_t)row * 768 + colp);
        }
      }
  } else {
    const int comp = brow0 / 768;              // uniform per block (128 | 768)
    const float qsc = (comp == 0) ? 0.125f : 1.0f;   // fold attention scale into Q
    const int b0r = arow0 / T_;
    const int RB = (b0r + 1) * T_;
    __syncthreads();
    if (comp < 2) {
      // Q/K: dump to LDS, then full-line 128B token-row writes (u16x4 x 16 lanes)
      u16* tl = &lds[0];                       // [128][136] u16
      #pragma unroll
      for (int m = 0; m < 4; ++m)
        #pragma unroll
        for (int n = 0; n < 4; ++n)
          #pragma unroll
          for (int rr = 0; rr < 4; ++rr)
            tl[(wr * 64 + m * 16 + lg * 4 + rr) * 136 + wc * 64 + n * 16 + li] =
                f2bf(acc[m][n][rr] * qsc);
      __syncthreads();
      u16* dst = (comp == 0) ? Qb : Kb;
      const int hh0 = (brow0 - comp * 768) >> 6;
      const int grp = tid >> 4, li2 = tid & 15;
      #pragma unroll
      for (int pass = 0; pass < 16; ++pass) {
        const int idx = pass * 16 + grp;
        const int row = idx >> 1, hl = idx & 1;
        const int rg = arow0 + row;
        if (rg >= M1) continue;
        const int bb = (rg >= RB) ? b0r + 1 : b0r;
        const int tt = rg - bb * T_;
        const size_t bh = (size_t)bb * H_ + hh0 + hl;
        *(u16x4*)(dst + ((bh * T_ + tt) << 6) + li2 * 4) =
            *(const u16x4*)(tl + row * 136 + hl * 64 + li2 * 4);
      }
    } else {
      // V: LDS transpose -> t-contiguous Vt row writes
      u16* tl = &lds[0];                       // [128][130] u16
      #pragma unroll
      for (int m = 0; m < 4; ++m)
        #pragma unroll
        for (int n = 0; n < 4; ++n)
          #pragma unroll
          for (int rr = 0; rr < 4; ++rr)
            tl[(wr * 64 + m * 16 + lg * 4 + rr) * 130 + wc * 64 + n * 16 + li] =
                f2bf(acc[m][n][rr]);
      __syncthreads();
      const int vcol0 = brow0 - 1536;
      #pragma unroll 1
      for (int cc = 0; cc < 32; ++cc) {
        const int c = wid * 32 + cc;
        const int vcol = vcol0 + c;
        const int hh = vcol >> 6, dd = vcol & 63;
        #pragma unroll
        for (int half = 0; half < 2; ++half) {
          const int tloc = half * 64 + lane;
          const int rg = arow0 + tloc;
          if (rg >= M1) continue;
          const int bb = (rg >= RB) ? b0r + 1 : b0r;
          const int tt = rg - bb * T_;
          Vt[(((size_t)bb * H_ + hh) * 64 + dd) * VSTR + tt] = tl[tloc * 130 + c];
        }
      }
    }
  }
}

// ---------------- spatial attention: one block per (b,f,h), 8 waves, K/V in LDS ----------------
// Chunked-P softmax: per 32-key chunk, exp from QK^T regs -> small per-wave P buffer
// (16x72, parity double-buffered cols) -> wave-sync lgkmcnt(0) -> PV MFMA.
// LDS 79,872 B <= 80KB -> 2 blocks/CU; launch_bounds(512,4) caps VGPR at 128.
__global__ __launch_bounds__(512, 4) void k_attn_sp(const u16* __restrict__ Qb,
                                                    const u16* __restrict__ Kb,
                                                    const u16* __restrict__ Vt,
                                                    u16* __restrict__ AO) {
  __shared__ u16 Ks[224 * 64];       // 28,672 B
  __shared__ u16 Vs[4 * 64 * 64];    // 32,768 B
  __shared__ u16 P[8][16 * 72];      // 18,432 B  (total 79,872 B)
  const int bid = blockIdx.x;
  const int h = bid % H_;
  const int f = (bid / H_) % F_;
  const int b = bid / (H_ * F_);
  const int tid = threadIdx.x;
  const int lane = tid & 63, w = tid >> 6;
  const int li = lane & 15, lg = lane >> 4;
  const size_t bh = (size_t)b * H_ + h;
  const u16* Qp = Qb + bh * T_ * 64;
  const u16* Kp = Kb + bh * T_ * 64;
  const u16* Vp = Vt + bh * 64 * VSTR;
  u16* ps = &P[w][0];

  if (w < 7) {
    #pragma unroll
    for (int p = 0; p < 4; ++p) {
      const int c = (w * 4 + p) * 64 + lane;        // 16B chunk id
      const int key = c >> 3, sp = lane & 7;
      const int tok = (key == 0) ? 0 : f * 196 + key;
      GLL(Kp + (size_t)tok * 64 + ((sp ^ (key & 7)) * 8), Ks + c * 8);
    }
  }
  {
    const int d = tid & 63, kg = (tid >> 6) & 3, sh = tid >> 8;
    #pragma unroll
    for (int st = 0; st < 2; ++st) {
      const int stt = sh + st * 2;
      const u16* src = Vp + (size_t)d * VSTR + f * 196 + stt * 64 + kg * 16;
      u16x4 a0 = *(const u16x4*)(src);
      u16x4 a1 = *(const u16x4*)(src + 4);
      u16x4 a2 = *(const u16x4*)(src + 8);
      u16x4 a3 = *(const u16x4*)(src + 12);
      if (stt == 0 && kg == 0) a0[0] = Vp[(size_t)d * VSTR];   // cls patch (t=0)
      u16* row = Vs + stt * 4096 + d * 64;
      const int s0 = (kg * 2) ^ (d & 7), s1 = (kg * 2 + 1) ^ (d & 7);
      u16x8 w0 = { a0[0], a0[1], a0[2], a0[3], a1[0], a1[1], a1[2], a1[3] };
      u16x8 w1 = { a2[0], a2[1], a2[2], a2[3], a3[0], a3[1], a3[2], a3[3] };
      *(u16x8*)(row + s0 * 8) = w0;
      *(u16x8*)(row + s1 * 8) = w1;
    }
  }
  __syncthreads();

  for (int mt = w; mt < 13; mt += 8) {
    const int pp = mt * 16 + li;
    const int ppc = pp < 196 ? pp : 195;
    const size_t tq = 1 + f * 196 + ppc;
    const bf16x8 qf0 = *(const bf16x8*)(Qp + tq * 64 + lg * 8);
    const bf16x8 qf1 = *(const bf16x8*)(Qp + tq * 64 + 32 + lg * 8);

    f32x4 s[14] = {};
    #pragma unroll
    for (int n = 0; n < 14; ++n) {
      const int key = n * 16 + li;
      const u16* kp = Ks + key * 64;
      const bf16x8 kf0 = *(const bf16x8*)(kp + ((lg ^ (li & 7)) * 8));
      const bf16x8 kf1 = *(const bf16x8*)(kp + (((lg + 4) ^ (li & 7)) * 8));
      s[n] = __builtin_amdgcn_mfma_f32_16x16x32_bf16(qf0, kf0, s[n], 0, 0, 0);
      s[n] = __builtin_amdgcn_mfma_f32_16x16x32_bf16(qf1, kf1, s[n], 0, 0, 0);
    }

    // masked row-max (in-register)
    float mx[4];
    #pragma unroll
    for (int r = 0; r < 4; ++r) {
      float m0 = -1e30f;
      #pragma unroll
      for (int n = 0; n < 14; ++n) {
        const int key = n * 16 + li;
        m0 = fmaxf(m0, (key < 197) ? s[n][r] : -1e30f);
      }
      #pragma unroll
      for (int msk = 1; msk < 16; msk <<= 1) m0 = fmaxf(m0, __shfl_xor(m0, msk));
      mx[r] = m0;
    }

    // chunked softmax-exp -> small P buffer -> PV, 32 keys at a time
    float rsum[4] = {0.f, 0.f, 0.f, 0.f};
    f32x4 o[4] = {};
    #pragma unroll
    for (int ks = 0; ks < 7; ++ks) {
      const int cofs = (ks & 1) * 32;          // parity double-buffer columns
      #pragma unroll
      for (int half = 0; half < 2; ++half) {
        const int n = ks * 2 + half;
        const int key = n * 16 + li;
        #pragma unroll
        for (int r = 0; r < 4; ++r) {
          float p = (key < 197) ? __expf(s[n][r] - mx[r]) : 0.f;
          rsum[r] += p;
          ps[(lg * 4 + r) * 72 + cofs + half * 16 + li] = f2bf(p);
        }
      }
      asm volatile("s_waitcnt lgkmcnt(0)" ::: "memory");   // wave-sync: writes visible
      const bf16x8 pf = *(const bf16x8*)(ps + li * 72 + cofs + lg * 8);
      const int slot = ((ks & 1) * 4 + lg);
      #pragma unroll
      for (int n = 0; n < 4; ++n) {
        const int d = n * 16 + li;
        const bf16x8 vf = *(const bf16x8*)(Vs + (ks >> 1) * 4096 + d * 64 +
                                           ((slot ^ (li & 7)) * 8));
        o[n] = __builtin_amdgcn_mfma_f32_16x16x32_bf16(pf, vf, o[n], 0, 0, 0);
      }
    }

    // finish row-sums
    #pragma unroll
    for (int r = 0; r < 4; ++r) {
      float su = rsum[r];
      #pragma unroll
      for (int msk = 1; msk < 16; msk <<= 1) su += __shfl_xor(su, msk);
      rsum[r] = su;
    }

    // AO epilogue: stage 16x64 tile in ps (stride 64 fits 16x72), full 128B rows
    asm volatile("s_waitcnt lgkmcnt(0)" ::: "memory");
    #pragma unroll
    for (int n = 0; n < 4; ++n)
      #pragma unroll
      for (int r = 0; r < 4; ++r)
        ps[(lg * 4 + r) * 64 + n * 16 + li] = f2bf(o[n][r] / rsum[r]);
    asm volatile("s_waitcnt lgkmcnt(0)" ::: "memory");
    #pragma unroll
    for (int p2 = 0; p2 < 2; ++p2) {
      const int row = p2 * 8 + (lane >> 3);
      const int ch = lane & 7;
      const int ppo = mt * 16 + row;
      if (ppo < 196) {
        const size_t t = 1 + (size_t)f * 196 + ppo;
        *(u16x8*)(AO + ((size_t)b * T_ + t) * 768 + h * 64 + ch * 8) =
            *(const u16x8*)(ps + row * 64 + ch * 8);
      }
    }
  }
}

// ---------------- cls attention, split-K pass 1 (Q pre-scaled; 16 splits) ----------------
__global__ __launch_bounds__(256) void k_attn_cls1(const u16* __restrict__ Qb,
                                                   const u16* __restrict__ Kb,
                                                   const u16* __restrict__ Vt,
                                                   float* __restrict__ Pc) {
  __shared__ float qs[64];
  __shared__ float sv[SPK];
  __shared__ float red[8];
  const int bid = blockIdx.x;
  const int s = bid & (NSPL - 1);
  const int bh = bid >> 4;
  const u16* Qp = Qb + (size_t)bh * T_ * 64;
  const u16* Kp = Kb + (size_t)bh * T_ * 64;
  const u16* Vp = Vt + (size_t)bh * 64 * VSTR;
  const int base = s * SPK;
  const int nk0 = T_ - base;
  const int nk = (nk0 < SPK) ? nk0 : SPK;
  const int tid = threadIdx.x;
  const int lane = tid & 63, w = tid >> 6;

  if (tid < 64) qs[tid] = b2f(Qp[tid]);
  for (int jj = nk + tid; jj < SPK; jj += 256) sv[jj] = 0.f;
  __syncthreads();

  float lmax = -1e30f;
  for (int jj = tid; jj < nk; jj += 256) {
    const u16* kp = Kp + (size_t)(base + jj) * 64;
    float acc = 0.f;
    #pragma unroll
    for (int d0 = 0; d0 < 64; d0 += 8) {
      u16x8 kv = *(const u16x8*)(kp + d0);
      #pragma unroll
      for (int e = 0; e < 8; ++e) acc += qs[d0 + e] * b2f(kv[e]);
    }
    sv[jj] = acc;
    lmax = fmaxf(lmax, acc);
  }
  #pragma unroll
  for (int msk = 32; msk; msk >>= 1) lmax = fmaxf(lmax, __shfl_xor(lmax, msk));
  if (lane == 0) red[w] = lmax;
  __syncthreads();
  const float bmax = fmaxf(fmaxf(red[0], red[1]), fmaxf(red[2], red[3]));

  float lsum = 0.f;
  for (int jj = tid; jj < nk; jj += 256) {
    float p = __expf(sv[jj] - bmax);
    sv[jj] = p;
    lsum += p;
  }
  #pragma unroll
  for (int msk = 32; msk; msk >>= 1) lsum += __shfl_xor(lsum, msk);
  if (lane == 0) red[4 + w] = lsum;
  __syncthreads();
  const float bsum = red[4] + red[5] + red[6] + red[7];

  const int d = tid >> 2, q4 = tid & 3;
  const u16* vp = Vp + (size_t)d * VSTR + base + q4 * (SPK / 4);
  const float* sp = &sv[q4 * (SPK / 4)];
  float o = 0.f;
  #pragma unroll
  for (int k4 = 0; k4 < SPK / 4; k4 += 4) {
    u16x4 vv = *(const u16x4*)(vp + k4);
    o += sp[k4]     * b2f(vv[0]) + sp[k4 + 1] * b2f(vv[1])
       + sp[k4 + 2] * b2f(vv[2]) + sp[k4 + 3] * b2f(vv[3]);
  }
  o += __shfl_xor(o, 1);
  o += __shfl_xor(o, 2);

  float* P = Pc + ((size_t)bh * NSPL + s) * 66;
  if (tid == 0) { P[0] = bmax; P[1] = bsum; }
  if (q4 == 0) P[2 + d] = o;
}

// ---------------- cls attention, split-K pass 2 ----------------
__global__ __launch_bounds__(64) void k_attn_cls2(const float* __restrict__ Pc,
                                                  u16* __restrict__ AO) {
  const int bh = blockIdx.x;
  const int d = threadIdx.x;
  const float* P = Pc + (size_t)bh * NSPL * 66;
  float m = -1e30f;
  #pragma unroll
  for (int s = 0; s < NSPL; ++s) m = fmaxf(m, P[s * 66]);
  float l = 0.f, o = 0.f;
  #pragma unroll
  for (int s = 0; s < NSPL; ++s) {
    const float wgt = __expf(P[s * 66] - m);
    l += wgt * P[s * 66 + 1];
    o += wgt * P[s * 66 + 2 + d];
  }
  const int b = bh / H_, h = bh - b * H_;
  AO[(size_t)b * T_ * 768 + h * 64 + d] = f2bf(o / l);
}

// ---------------- launch ----------------
extern "C" void kernel_launch(void* const* d_in, const int* in_sizes, int n_in,
                              void* d_out, int out_size, void* d_ws, size_t ws_size,
                              hipStream_t stream) {
  const float* x    = (const float*)d_in[0];
  const float* Wqkv = (const float*)d_in[1];
  const float* W0   = (const float*)d_in[2];
  float* out = (float*)d_out;
  char* ws = (char*)d_ws;

  u16* xb    = (u16*)(ws);                  // 25216*768*2 ; reused as AO
  u16* wqkvT = (u16*)(ws + 38731776);       // reused as Pc
  u16* w0T   = (u16*)(ws + 42270720);
  u16* Qb    = (u16*)(ws + 43450368);
  u16* Kb    = (u16*)(ws + 81997824);
  u16* Vt    = (u16*)(ws + 120545280);
  u16* AO = xb;
  float* Pc = (float*)wqkvT;

  k_cvt_x<<<dim3(18822), dim3(256), 0, stream>>>(x, xb, (M1 * D_) / 4);
  k_transpose<<<dim3(72, 24), dim3(32, 8), 0, stream>>>(Wqkv, wqkvT, 768, 2304, 1);
  k_transpose<<<dim3(24, 24), dim3(32, 8), 0, stream>>>(W0, w0T, 768, 768, 0);
  k_gemm<1, 18><<<dim3(18 * 197), dim3(256), 0, stream>>>(xb, wqkvT, nullptr, Qb, Kb, Vt);
  k_attn_sp<<<dim3(1536), dim3(512), 0, stream>>>(Qb, Kb, Vt, AO);
  k_attn_cls1<<<dim3(96 * NSPL), dim3(256), 0, stream>>>(Qb, Kb, Vt, Pc);
  k_attn_cls2<<<dim3(96), dim3(64), 0, stream>>>(Pc, AO);
  k_gemm<0, 6><<<dim3(6 * 197), dim3(256), 0, stream>>>(AO, w0T, out, nullptr, nullptr, nullptr);
}